// Round 7
// baseline (24.076 us; speedup 1.0000x reference)
//
#include <hip/hip_runtime.h>
#include <hip/hip_bf16.h>
#include <math.h>

// max_{n,m} ||L[n]-R[m]||, L,R: [8192][64] fp32.
// R7: ONE-SHOT blocks — no m-loop, no double-buffer, 2 barriers total.
// Block tile 128m x 256n (grid 64x32 = 2048 blocks, 2 resident/CU; block-level
// pipelining: block i+1 stages while block i computes). A staged to LDS via
// global_load_lds; B split nj={0,1} regs / nj={2,3} LDS (validated R6).
// Prepack converts fp32->bf16 frag-packed once (+ exact fp32 norms).

typedef __attribute__((ext_vector_type(8)))  short  short8;   // bf16x8 frag
typedef __attribute__((ext_vector_type(4)))  float  f32x4;
typedef __attribute__((ext_vector_type(16))) float  f32x16;   // 32x32 accum

constexpr int D  = 64;
constexpr int NR = 8192;
constexpr int GX = 32;          // n-dim grid (256 cols each)
constexpr int GY = 64;          // m-dim grid (128 rows each)
constexpr int NSLOT = GX * GY;  // 2048

__device__ __forceinline__ short f2bf(float f) {
    __hip_bfloat16 h = __float2bfloat16(f);
    return __builtin_bit_cast(short, h);
}

// Frag-packed layout: row r, k-chunk kk (16 k's), k-half kh, elem e:
//   short index = ((r>>5)*4 + kk)*512 + (kh*32 + (r&31))*8 + e
// -> a wave's frag access at [group][kk] + lane*8 is contiguous 1KB.

// ---- prepack: 1 thread per (row, 8-float half-chunk); 8 threads/row ----
__global__ __launch_bounds__(256) void prepack_kernel(
    const float* __restrict__ L, const float* __restrict__ R,
    short* __restrict__ Apk, short* __restrict__ Bpk,
    float* __restrict__ lsq, float* __restrict__ rsq)
{
    const int t = blockIdx.x * 256 + threadIdx.x;   // 0..131071
    const int r = t >> 3;                           // 0..16383
    const int j = t & 7;                            // half-chunk
    const int kk = j >> 1, kh = j & 1;
    const bool isL = (r < NR);
    const int rr = isL ? r : r - NR;

    const float* src = (isL ? L : R) + (size_t)rr * D + j * 8;
    short* pk = isL ? Apk : Bpk;

    f32x4 v0 = *reinterpret_cast<const f32x4*>(src + 0);
    f32x4 v1 = *reinterpret_cast<const f32x4*>(src + 4);

    float p = 0.f;
    #pragma unroll
    for (int e = 0; e < 4; ++e) { p = fmaf(v0[e], v0[e], p); p = fmaf(v1[e], v1[e], p); }

    short8 w;
    #pragma unroll
    for (int e = 0; e < 4; ++e) { w[e] = f2bf(v0[e]); w[4+e] = f2bf(v1[e]); }
    *reinterpret_cast<short8*>(
        pk + ((size_t)(rr >> 5) * 4 + kk) * 512 + (kh * 32 + (rr & 31)) * 8) = w;

    // row norm across the 8-thread group (consecutive lanes)
    p += __shfl_xor(p, 1, 64);
    p += __shfl_xor(p, 2, 64);
    p += __shfl_xor(p, 4, 64);
    if (j == 0) (isL ? lsq : rsq)[rr] = p;
}

// ---- main: 4 waves (2x2), block 128m x 256n one-shot, wave 64m x 128n ----
__global__ __launch_bounds__(256, 2) void pairdist_mfma_kernel(
    const short* __restrict__ Apk, const short* __restrict__ Bpk,
    const float* __restrict__ lsq, const float* __restrict__ rsq,
    float* __restrict__ slots)
{
    __shared__ __align__(16) short A_lds[4][4][64][8];   // 16 KiB (128 rows)
    __shared__ __align__(16) short B_lds[4][4][64][8];   // 16 KiB (groups {2,3,6,7})
    __shared__ __align__(16) float lsq_s[128];
    __shared__ __align__(16) float rsq_s[256];
    __shared__ float wmax_s[4];

    const int tid  = threadIdx.x;
    const int lane = tid & 63;
    const int wave = tid >> 6;
    const int yb = blockIdx.x;     // 0..31 -> 256-col chunk of R
    const int xc = blockIdx.y;     // 0..63 -> 128-row chunk of L

    // stage A (16 x 1KB): wave handles kk=wave, group i=0..3
    {
        const short* At = Apk + (size_t)(xc * 4) * 2048;
        #pragma unroll
        for (int i = 0; i < 4; ++i)
            __builtin_amdgcn_global_load_lds(
                (const __attribute__((address_space(1))) unsigned int*)
                    (At + ((size_t)i * 4 + wave) * 512 + lane * 8),
                (__attribute__((address_space(3))) unsigned int*)
                    (&A_lds[i][wave][0][0]),
                16, 0, 0);
    }
    // stage B groups {2,3,6,7} (slots 0..3): wave handles kk=wave
    {
        #pragma unroll
        for (int s = 0; s < 4; ++s) {
            const int gsrc = yb * 8 + (s >> 1) * 4 + 2 + (s & 1);
            __builtin_amdgcn_global_load_lds(
                (const __attribute__((address_space(1))) unsigned int*)
                    (Bpk + ((size_t)gsrc * 4 + wave) * 512 + lane * 8),
                (__attribute__((address_space(3))) unsigned int*)
                    (&B_lds[s][wave][0][0]),
                16, 0, 0);
        }
    }

    if (tid < 128) lsq_s[tid] = lsq[xc * 128 + tid];
    rsq_s[tid] = rsq[yb * 256 + tid];

    const int wm = wave >> 1;      // 64-row half of 128
    const int wn = wave & 1;       // 128-col half of 256
    // B-frags nj=0,1 in registers (8 x dwordx4)
    short8 bf[2][4];
    #pragma unroll
    for (int nj = 0; nj < 2; ++nj)
        #pragma unroll
        for (int kk = 0; kk < 4; ++kk)
            bf[nj][kk] = *reinterpret_cast<const short8*>(
                Bpk + ((size_t)(yb * 8 + wn * 4 + nj) * 4 + kk) * 512 + lane * 8);

    __syncthreads();   // barrier 1: staging complete

    const int col = lane & 31;
    const int h   = lane >> 5;
    float rq[4];
    #pragma unroll
    for (int nj = 0; nj < 4; ++nj) rq[nj] = rsq_s[wn * 128 + nj * 32 + col];

    f32x16 acc[2][4] = {};
    #pragma unroll
    for (int kk = 0; kk < 4; ++kk) {
        short8 a0 = *reinterpret_cast<const short8*>(&A_lds[wm*2+0][kk][lane][0]);
        short8 a1 = *reinterpret_cast<const short8*>(&A_lds[wm*2+1][kk][lane][0]);
        short8 b2 = *reinterpret_cast<const short8*>(&B_lds[wn*2+0][kk][lane][0]);
        short8 b3 = *reinterpret_cast<const short8*>(&B_lds[wn*2+1][kk][lane][0]);
        acc[0][0] = __builtin_amdgcn_mfma_f32_32x32x16_bf16(a0, bf[0][kk], acc[0][0], 0, 0, 0);
        acc[0][1] = __builtin_amdgcn_mfma_f32_32x32x16_bf16(a0, bf[1][kk], acc[0][1], 0, 0, 0);
        acc[0][2] = __builtin_amdgcn_mfma_f32_32x32x16_bf16(a0, b2,        acc[0][2], 0, 0, 0);
        acc[0][3] = __builtin_amdgcn_mfma_f32_32x32x16_bf16(a0, b3,        acc[0][3], 0, 0, 0);
        acc[1][0] = __builtin_amdgcn_mfma_f32_32x32x16_bf16(a1, bf[0][kk], acc[1][0], 0, 0, 0);
        acc[1][1] = __builtin_amdgcn_mfma_f32_32x32x16_bf16(a1, bf[1][kk], acc[1][1], 0, 0, 0);
        acc[1][2] = __builtin_amdgcn_mfma_f32_32x32x16_bf16(a1, b2,        acc[1][2], 0, 0, 0);
        acc[1][3] = __builtin_amdgcn_mfma_f32_32x32x16_bf16(a1, b3,        acc[1][3], 0, 0, 0);
    }

    // epilogue: sq = lsq[row] + rsq[col] - 2*dot, balanced max tree.
    // C layout (32x32): col = lane&31, row = (reg&3) + 8*(reg>>2) + 4*(lane>>5)
    float lmax = 0.f;
    #pragma unroll
    for (int mi = 0; mi < 2; ++mi) {
        const int rbase = (wm * 2 + mi) * 32 + 4 * h;
        f32x4 lq[4];
        lq[0] = *reinterpret_cast<const f32x4*>(&lsq_s[rbase +  0]);
        lq[1] = *reinterpret_cast<const f32x4*>(&lsq_s[rbase +  8]);
        lq[2] = *reinterpret_cast<const f32x4*>(&lsq_s[rbase + 16]);
        lq[3] = *reinterpret_cast<const f32x4*>(&lsq_s[rbase + 24]);
        #pragma unroll
        for (int nj = 0; nj < 4; ++nj) {
            float x[16];
            #pragma unroll
            for (int g = 0; g < 4; ++g)
                #pragma unroll
                for (int e = 0; e < 4; ++e)
                    x[g*4+e] = fmaf(-2.f, acc[mi][nj][g*4+e], lq[g][e]);
            float y0 = fmaxf(x[0],  x[1]),  y1 = fmaxf(x[2],  x[3]);
            float y2 = fmaxf(x[4],  x[5]),  y3 = fmaxf(x[6],  x[7]);
            float y4 = fmaxf(x[8],  x[9]),  y5 = fmaxf(x[10], x[11]);
            float y6 = fmaxf(x[12], x[13]), y7 = fmaxf(x[14], x[15]);
            float z0 = fmaxf(y0, y1), z1 = fmaxf(y2, y3);
            float z2 = fmaxf(y4, y5), z3 = fmaxf(y6, y7);
            float m  = fmaxf(fmaxf(z0, z1), fmaxf(z2, z3));
            lmax = fmaxf(lmax, m + rq[nj]);
        }
    }

    #pragma unroll
    for (int off = 32; off >= 1; off >>= 1)
        lmax = fmaxf(lmax, __shfl_xor(lmax, off, 64));
    if (lane == 0) wmax_s[wave] = lmax;
    __syncthreads();   // barrier 2: cross-wave reduce
    if (tid == 0) {
        float bmax = fmaxf(fmaxf(wmax_s[0], wmax_s[1]), fmaxf(wmax_s[2], wmax_s[3]));
        slots[blockIdx.y * GX + blockIdx.x] = fmaxf(bmax, 0.f);
    }
}

// ---- finalize: reduce 2048 slots, sqrt, write scalar ----
__global__ __launch_bounds__(512) void finalize_kernel(
    const float* __restrict__ slots, float* __restrict__ out)
{
    __shared__ float wred[8];
    const int tid = threadIdx.x;
    float v = slots[tid];
    #pragma unroll
    for (int i = 1; i < NSLOT / 512; ++i)
        v = fmaxf(v, slots[tid + i * 512]);
    #pragma unroll
    for (int off = 32; off >= 1; off >>= 1)
        v = fmaxf(v, __shfl_xor(v, off, 64));
    if ((tid & 63) == 0) wred[tid >> 6] = v;
    __syncthreads();
    if (tid == 0) {
        float m = wred[0];
        #pragma unroll
        for (int i = 1; i < 8; ++i) m = fmaxf(m, wred[i]);
        out[0] = sqrtf(m);
    }
}

extern "C" void kernel_launch(void* const* d_in, const int* in_sizes, int n_in,
                              void* d_out, int out_size, void* d_ws, size_t ws_size,
                              hipStream_t stream) {
    const float* L = (const float*)d_in[0];
    const float* R = (const float*)d_in[1];

    short* Apk = (short*)d_ws;
    short* Bpk = Apk + (size_t)NR * D;           // 524288 shorts each
    float* lsqg = (float*)(Bpk + (size_t)NR * D);
    float* rsqg = lsqg + NR;
    float* slots = rsqg + NR;

    prepack_kernel<<<(2 * NR * 8) / 256, 256, 0, stream>>>(L, R, Apk, Bpk, lsqg, rsqg);
    pairdist_mfma_kernel<<<dim3(GX, GY), dim3(256), 0, stream>>>(Apk, Bpk, lsqg, rsqg, slots);
    finalize_kernel<<<1, 512, 0, stream>>>(slots, (float*)d_out);
}